// Round 13
// baseline (198.698 us; speedup 1.0000x reference)
//
#include <hip/hip_runtime.h>

#define NGRAPH 1000
#define P      100
#define EPG    1200
#define INF    16
#define HID    64
#define NOUT   5

// r31 = r30 (M-split W-phase) with ONE parameter change: __launch_bounds__
// (256,4) -> (256,3) on gnn_kernel.
//  - r30 post-mortem: M-split MECHANISM CONFIRMED (VALUBusy 56->33,
//    conflicts 8.1e6->5.1e6) but W-phase reg demand (~130-150: 32 acc f32 +
//    4 transient short8 frags + B-frags + addressing) exceeded the 128-reg
//    cap of (256,4) -> 10MB spill (WRITE 47KB->10MB), dur 82->95.
//  - (256,3): cap ~170 regs. Occupancy nominally 4->3 blocks/CU, but
//    MEASURED occupancy was already ~36-40% = ~3 blocks/CU (1000 blocks /
//    256 CUs with tail) -> real cost ~nil.
//  - r25's (256,3) spill does not apply: that demand (persistent frags
//    across all layers) was far above 170; r30's transient demand is not.
//  - REVERT TRIGGER (pre-committed): WRITE_SIZE in MBs or dur >= 82us ->
//    restore r28 next round and close.
// All code below is r30 verbatim except the launch bound.

#define ASTR   100
#define DINVC  64
#define DEGC   65
#define T1OFF  68
#define T2OFF  84

#define AINT_K   128
#define AINT_SZ  (P * AINT_K)     // 12800 shorts per graph

// wt table offsets (shorts). L1: RK=64 (48 real + 16 zero). L2/L3: RK=208.
#define RK1    64
#define RK2    208
#define L1HI   0
#define L1LO   4096
#define L2HI   8192
#define L2LO   21504
#define L3HI   34816
#define L3LO   48128
#define WT_SHORTS 61440

typedef short short8 __attribute__((ext_vector_type(8)));
typedef float f32x4  __attribute__((ext_vector_type(4)));

__device__ __forceinline__ void bsplit(float x, short& h, short& l) {
    unsigned u = __float_as_uint(x);
    h = (short)(u >> 16);
    float hf = __uint_as_float(u & 0xffff0000u);
    l = (short)(__float_as_uint(x - hf) >> 16);
}

// ---- merged pre-kernel: W split/transpose + per-graph adjacency build ----
__global__ __launch_bounds__(256) void prep(
    const float* __restrict__ W1, const float* __restrict__ W2,
    const float* __restrict__ W3, short* __restrict__ wt,
    const int* __restrict__ src, const int* __restrict__ dst,
    short* __restrict__ aint)
{
    const int tid = threadIdx.x;
    {
        const int i0 = blockIdx.x * blockDim.x + tid;
        const int stride = gridDim.x * blockDim.x;
        for (int e = i0; e < HID * RK1; e += stride) {
            int c = e / RK1, r = e % RK1;
            float v = (r < 3 * INF) ? W1[r * HID + c] : 0.f;
            short h, l; bsplit(v, h, l);
            wt[L1HI + e] = h;
            wt[L1LO + e] = l;
        }
        for (int e = i0; e < HID * RK2; e += stride) {
            int c = e / RK2, r = e % RK2;
            float v2 = (r < 3 * HID) ? W2[r * HID + c] : 0.f;
            float v3 = (r < 3 * HID) ? W3[r * HID + c] : 0.f;
            short h, l;
            bsplit(v2, h, l); wt[L2HI + e] = h; wt[L2LO + e] = l;
            bsplit(v3, h, l); wt[L3HI + e] = h; wt[L3LO + e] = l;
        }
    }
    __shared__ unsigned int cnt[AINT_SZ / 2];     // 25,600 B
    const int g = blockIdx.x, base = g * P;
    for (int i = tid; i < AINT_SZ / 2; i += 256) cnt[i] = 0u;
    __syncthreads();
    const int* srcg = src + g * EPG;
    const int* dstg = dst + g * EPG;
    for (int e = tid; e < EPG; e += 256) {
        int s = srcg[e] - base;
        int d = dstg[e] - base;
        int idx = d * AINT_K + s;
        atomicAdd(&cnt[idx >> 1], 1u << ((idx & 1) * 16));
    }
    __syncthreads();
    unsigned int* outw = (unsigned int*)(aint + (size_t)g * AINT_SZ);
    for (int i = tid; i < AINT_SZ / 2; i += 256) {
        unsigned int u = cnt[i];
        unsigned int b0 = __float_as_uint((float)(u & 0xffffu)) >> 16;
        unsigned int b1 = __float_as_uint((float)(u >> 16)) >> 16;
        outw[i] = b0 | (b1 << 16);
    }
}

// ---- one dense propagation (r19/r28 verbatim) ----
template <int SECOND>
__device__ __forceinline__ void dense_prop(
    float* __restrict__ A, const short* __restrict__ aintg,
    int arow0, int arow1, bool has2,
    int srcoff, int dstoff, int ycol,
    int rb0, int rb1, f32x4 dv0, f32x4 dv1, int lane)
{
    const int n16 = lane & 15;
    const int q   = lane >> 4;
    const int kq  = q * 8;
    f32x4 p0, p1;
    p0[0]=0.f; p0[1]=0.f; p0[2]=0.f; p0[3]=0.f;
    p1[0]=0.f; p1[1]=0.f; p1[2]=0.f; p1[3]=0.f;
#pragma unroll
    for (int k = 0; k < 4; k++) {
        const short8 a0 = *(const short8*)&aintg[arow0 * AINT_K + k * 32 + kq];
        const short8 a1 = *(const short8*)&aintg[arow1 * AINT_K + k * 32 + kq];
        short8 bhi, blo; short h, l;
#pragma unroll
        for (int j = 0; j < 8; j++) {
            int row = k * 32 + kq + j;
            if (k == 3) row = (row < P) ? row : 0;   // Aint cols >=100 are 0
            float x = A[row * ASTR + srcoff + n16];
            bsplit(x, h, l); bhi[j] = h; blo[j] = l;
        }
        p0 = __builtin_amdgcn_mfma_f32_16x16x32_bf16(a0, bhi, p0, 0, 0, 0);
        p0 = __builtin_amdgcn_mfma_f32_16x16x32_bf16(a0, blo, p0, 0, 0, 0);
        if (has2) {
            p1 = __builtin_amdgcn_mfma_f32_16x16x32_bf16(a1, bhi, p1, 0, 0, 0);
            p1 = __builtin_amdgcn_mfma_f32_16x16x32_bf16(a1, blo, p1, 0, 0, 0);
        }
    }
#pragma unroll
    for (int r = 0; r < 4; r++) {
        const int row = rb0 + q * 4 + r;
        const float d2 = dv0[r] * dv0[r];
        float o;
        if (SECOND) o = -2.f * d2 * p0[r] - A[row * ASTR + ycol];
        else        o = -d2 * p0[r];
        A[row * ASTR + dstoff + n16] = o;
    }
    if (has2) {
#pragma unroll
        for (int r = 0; r < 4; r++) {
            const int row = rb1 + q * 4 + r;
            if (rb1 != 84 || row >= 96) {            // tile-6 overlap guard
                const float d2 = dv1[r] * dv1[r];
                float o;
                if (SECOND) o = -2.f * d2 * p1[r] - A[row * ASTR + ycol];
                else        o = -d2 * p1[r];
                A[row * ASTR + dstoff + n16] = o;
            }
        }
    }
}

// ---- one ChebConv layer: props (unchanged mapping) + M-split W matmul ----
template <int F, int FINAL>
__device__ __forceinline__ void cheb_layer(
    float* __restrict__ A, const short* __restrict__ aintg,
    const short* __restrict__ whi, const short* __restrict__ wlo,
    const float* __restrict__ bias,
    int tid, int rb0, int rb1, bool has2, f32x4 dv0, f32x4 dv1)
{
    const int RK   = 3 * F + 16;
    const int lane = tid & 63;
    const int wv   = tid >> 6;
    const int n16  = lane & 15;
    const int q    = lane >> 4;

    const int arow0 = rb0 + n16;                 // prop mapping (unchanged)
    const int arow1 = (has2 ? rb1 : rb0) + n16;

    // M-split: wave wv owns row-tiles t0 (and t0+1 if wv<3); wv3 -> tile 6
    const bool two  = (wv < 3);
    const int t0    = two ? wv * 2 : 6;
    const int rbo0  = (t0 < 6) ? t0 * 16 : 84;   // output row base, tile 0
    const int rbo1  = rbo0 + 16;                 // tile 1 (only if two)

    f32x4 acc[8];   // [mt*4 + nt], compile-time indexed after unroll
#pragma unroll
    for (int i = 0; i < 8; i++) { acc[i][0]=0.f; acc[i][1]=0.f; acc[i][2]=0.f; acc[i][3]=0.f; }

    for (int cb = 0; cb < F; cb += 16) {
        dense_prop<0>(A, aintg, arow0, arow1, has2, cb,    T1OFF, 0,
                      rb0, rb1, dv0, dv1, lane);
        __syncthreads();
        dense_prop<1>(A, aintg, arow0, arow1, has2, T1OFF, T2OFF, cb + n16,
                      rb0, rb1, dv0, dv1, lane);
        __syncthreads();

        // W partial: chunk K-layout [Y16 | T1_16 | T2_16 | zero16], 2 K-steps
#pragma unroll
        for (int ks = 0; ks < 2; ks++) {
            int wr, aoff;
            if (ks == 0) {
                wr   = (q == 0) ? cb : (q == 1) ? cb + 8 : (q == 2) ? F + cb : F + cb + 8;
                aoff = (q == 0) ? cb : (q == 1) ? cb + 8 : (q == 2) ? T1OFF  : T1OFF + 8;
            } else {
                wr   = (q == 0) ? 2*F + cb : (q == 1) ? 2*F + cb + 8 : (q == 2) ? 3*F : 3*F + 8;
                aoff = (q == 0) ? T2OFF    : (q == 1) ? T2OFF + 8    : (q == 2) ? T1OFF : T1OFF + 8;
            }
            // A fragment, my tile 0 (rows rbo0 + n16)
            short8 ahi0, alo0; short h, l;
            {
                const float* xp = &A[(rbo0 + n16) * ASTR + aoff];
                const float4 v0 = *(const float4*)xp;
                const float4 v1 = *(const float4*)(xp + 4);
                bsplit(v0.x, h, l); ahi0[0] = h; alo0[0] = l;
                bsplit(v0.y, h, l); ahi0[1] = h; alo0[1] = l;
                bsplit(v0.z, h, l); ahi0[2] = h; alo0[2] = l;
                bsplit(v0.w, h, l); ahi0[3] = h; alo0[3] = l;
                bsplit(v1.x, h, l); ahi0[4] = h; alo0[4] = l;
                bsplit(v1.y, h, l); ahi0[5] = h; alo0[5] = l;
                bsplit(v1.z, h, l); ahi0[6] = h; alo0[6] = l;
                bsplit(v1.w, h, l); ahi0[7] = h; alo0[7] = l;
            }
            // A fragment, my tile 1 (only waves 0..2)
            short8 ahi1, alo1;
            if (two) {
                const float* xp = &A[(rbo1 + n16) * ASTR + aoff];
                const float4 v0 = *(const float4*)xp;
                const float4 v1 = *(const float4*)(xp + 4);
                bsplit(v0.x, h, l); ahi1[0] = h; alo1[0] = l;
                bsplit(v0.y, h, l); ahi1[1] = h; alo1[1] = l;
                bsplit(v0.z, h, l); ahi1[2] = h; alo1[2] = l;
                bsplit(v0.w, h, l); ahi1[3] = h; alo1[3] = l;
                bsplit(v1.x, h, l); ahi1[4] = h; alo1[4] = l;
                bsplit(v1.y, h, l); ahi1[5] = h; alo1[5] = l;
                bsplit(v1.z, h, l); ahi1[6] = h; alo1[6] = l;
                bsplit(v1.w, h, l); ahi1[7] = h; alo1[7] = l;
            }
            // all 4 output col-tiles per wave (B from L2-resident wt tables)
#pragma unroll
            for (int nt = 0; nt < 4; nt++) {
                const int ncol = nt * 16 + n16;
                const short8 bhi = *(const short8*)&whi[ncol * RK + wr];
                const short8 blo = *(const short8*)&wlo[ncol * RK + wr];
                acc[nt] = __builtin_amdgcn_mfma_f32_16x16x32_bf16(ahi0, bhi, acc[nt], 0, 0, 0);
                acc[nt] = __builtin_amdgcn_mfma_f32_16x16x32_bf16(ahi0, blo, acc[nt], 0, 0, 0);
                acc[nt] = __builtin_amdgcn_mfma_f32_16x16x32_bf16(alo0, bhi, acc[nt], 0, 0, 0);
                if (two) {
                    acc[4+nt] = __builtin_amdgcn_mfma_f32_16x16x32_bf16(ahi1, bhi, acc[4+nt], 0, 0, 0);
                    acc[4+nt] = __builtin_amdgcn_mfma_f32_16x16x32_bf16(ahi1, blo, acc[4+nt], 0, 0, 0);
                    acc[4+nt] = __builtin_amdgcn_mfma_f32_16x16x32_bf16(alo1, bhi, acc[4+nt], 0, 0, 0);
                }
            }
        }
        __syncthreads();
    }

    // Epilogue (D: col=lane&15, row=4*(lane>>4)+reg), M-split tiles.
#pragma unroll
    for (int nt = 0; nt < 4; nt++) {
        const int ncol = nt * 16 + n16;
        const float bcol = bias[ncol];
#pragma unroll
        for (int r = 0; r < 4; r++) {
            const int row = rbo0 + q * 4 + r;
            if (t0 < 6 || row >= 96) {               // tile-6 guard (wv3)
                const float dn = A[row * ASTR + DINVC];
                const float v = acc[nt][r];
                float o;
                if (FINAL) o = fmaxf(v * (1.0f / dn) + bcol, 0.f);
                else       o = fmaxf(v + bcol * dn, 0.f);
                A[row * ASTR + ncol] = o;
            }
        }
        if (two) {
#pragma unroll
            for (int r = 0; r < 4; r++) {
                const int row = rbo1 + q * 4 + r;
                const float dn = A[row * ASTR + DINVC];
                const float v = acc[4+nt][r];
                float o;
                if (FINAL) o = fmaxf(v * (1.0f / dn) + bcol, 0.f);
                else       o = fmaxf(v + bcol * dn, 0.f);
                A[row * ASTR + ncol] = o;
            }
        }
    }
    __syncthreads();
}

__global__ __launch_bounds__(256, 3) void gnn_kernel(
    const float* __restrict__ feat,
    const int* __restrict__ src, const int* __restrict__ dst,
    const float* __restrict__ b1, const float* __restrict__ b2,
    const float* __restrict__ b3,
    const float* __restrict__ Wfc, const float* __restrict__ bfc,
    const short* __restrict__ wt, const short* __restrict__ aint,
    float* __restrict__ out)
{
    __shared__ __align__(16) float A[P * ASTR];   // 40,000 B
    const int g = blockIdx.x;
    const int tid = threadIdx.x;
    const int base = g * P;
    const int* dstg = dst + g * EPG;

    // ---- degree count (col DEGC) ----
    for (int i = tid; i < P; i += 256) *(int*)&A[i * ASTR + DEGC] = 0;
    __syncthreads();
    for (int e = tid; e < EPG; e += 256) {
        int d = dstg[e] - base;
        atomicAdd((int*)&A[d * ASTR + DEGC], 1);
    }
    __syncthreads();
    for (int i = tid; i < P; i += 256) {
        int dg = *(int*)&A[i * ASTR + DEGC];
        A[i * ASTR + DINVC] = rsqrtf((float)(dg > 1 ? dg : 1));
    }
    __syncthreads();

    // ---- feat load prescaled (A = dinv*feat) ----
    for (int i = tid; i < P * INF / 4; i += 256) {
        int n = i >> 2, fq = (i & 3) * 4;
        float4 v = *(const float4*)&feat[(size_t)base * INF + i * 4];
        float dn = A[n * ASTR + DINVC];
        v.x *= dn; v.y *= dn; v.z *= dn; v.w *= dn;
        *(float4*)&A[n * ASTR + fq] = v;
    }
    __syncthreads();

    // ---- per-wave tile assignment + dinv preload for prop epilogues ----
    const int lane = tid & 63, wv = tid >> 6, q = lane >> 4;
    const int rb0 = wv * 16;
    const int t2i = wv + 4;
    const int rb1 = (t2i >= 6) ? 84 : t2i * 16;
    const bool has2 = (wv < 3);
    f32x4 dv0, dv1;
#pragma unroll
    for (int r = 0; r < 4; r++) {
        dv0[r] = A[(rb0 + q * 4 + r) * ASTR + DINVC];
        dv1[r] = A[((has2 ? rb1 : rb0) + q * 4 + r) * ASTR + DINVC];
    }

    const short* aintg = aint + (size_t)g * AINT_SZ;
    cheb_layer<INF, 0>(A, aintg, wt + L1HI, wt + L1LO, b1, tid, rb0, rb1, has2, dv0, dv1);
    cheb_layer<HID, 0>(A, aintg, wt + L2HI, wt + L2LO, b2, tid, rb0, rb1, has2, dv0, dv1);
    cheb_layer<HID, 1>(A, aintg, wt + L3HI, wt + L3LO, b3, tid, rb0, rb1, has2, dv0, dv1);

    // ---- mean pool + FC (psum in the now-free T1/T2 slots) ----
    {
        const int l2 = tid & 63, w = tid >> 6;
        float s = 0.f;
        for (int n = w; n < P; n += 4) s += A[n * ASTR + l2];
        A[l2 * ASTR + T1OFF + w] = s;
    }
    __syncthreads();
    if (tid < HID) {
        float hg = (A[tid * ASTR + T1OFF] + A[tid * ASTR + T1OFF + 1] +
                    A[tid * ASTR + T1OFF + 2] + A[tid * ASTR + T1OFF + 3]) * (1.0f / P);
        A[tid * ASTR + T1OFF + 4] = hg;
    }
    __syncthreads();
    if (tid < NOUT) {
        float o = bfc[tid];
        for (int c = 0; c < HID; c++) o += A[c * ASTR + T1OFF + 4] * Wfc[c * NOUT + tid];
        out[g * NOUT + tid] = o;
    }
}

extern "C" void kernel_launch(void* const* d_in, const int* in_sizes, int n_in,
                              void* d_out, int out_size, void* d_ws, size_t ws_size,
                              hipStream_t stream)
{
    const float* feat = (const float*)d_in[0];
    const int*   src  = (const int*)d_in[1];
    const int*   dst  = (const int*)d_in[2];
    const float* W1  = (const float*)d_in[5];
    const float* b1  = (const float*)d_in[6];
    const float* W2  = (const float*)d_in[7];
    const float* b2  = (const float*)d_in[8];
    const float* W3  = (const float*)d_in[9];
    const float* b3  = (const float*)d_in[10];
    const float* Wfc = (const float*)d_in[11];
    const float* bfc = (const float*)d_in[12];
    float* out = (float*)d_out;

    short* wt   = (short*)d_ws;                 // 122,880 B
    short* aint = wt + WT_SHORTS;               // + 25,600,000 B

    prep<<<NGRAPH, 256, 0, stream>>>(W1, W2, W3, wt, src, dst, aint);
    gnn_kernel<<<NGRAPH, 256, 0, stream>>>(feat, src, dst,
                                           b1, b2, b3, Wfc, bfc, wt, aint, out);
}

// Round 14
// 159.770 us; speedup vs baseline: 1.2436x; 1.2436x over previous
//
#include <hip/hip_runtime.h>

#define NGRAPH 1000
#define P      100
#define EPG    1200
#define INF    16
#define HID    64
#define NOUT   5

// r32 = r28 RESTORED (measured session best: 159.1us total / gnn 82.0us /
// WRITE 47KB / VGPR 64). Final state.
// 13-round session summary:
//  - Dense-MFMA propagation (adjacency as bf16 count matrix, per-graph) and
//    merged prep dispatch: the two real wins (186.8 -> 159.1us).
//  - Every other axis regressed via compiler register-allocation pathology:
//    * packed-u32 / v_perm / bit_cast fragment builds -> 40-90MB scratch
//    * persistent cross-barrier frags -> 40-93MB scratch
//    * dual bf16 planes -> 47MB scratch
//    * addr swizzles in this frame -> +23MB spill, conflicts unchanged
//    * M-split W-phase @ (256,4): mechanism confirmed (VALUBusy 56->33) but
//      64 VGPR + 64 AGPR acc = 128 hits the cap -> 10MB spill, 95us
//    * M-split @ (256,3): spill gone (72+64=136<170) but 4->3 blocks/CU
//      occupancy loss -> 120us. Structural tension; no fit.
//  - Raw fp32 LDS + inline bsplit + per-prop adjacency loads is the unique
//    codegen-clean configuration; remaining headroom (MfmaUtil 21%) is not
//    reachable from HIP source on this toolchain by any explored path.

#define ASTR   100
#define DINVC  64
#define DEGC   65
#define T1OFF  68
#define T2OFF  84

#define AINT_K   128
#define AINT_SZ  (P * AINT_K)     // 12800 shorts per graph

// wt table offsets (shorts). L1: RK=64 (48 real + 16 zero). L2/L3: RK=208.
#define RK1    64
#define RK2    208
#define L1HI   0
#define L1LO   4096
#define L2HI   8192
#define L2LO   21504
#define L3HI   34816
#define L3LO   48128
#define WT_SHORTS 61440

typedef short short8 __attribute__((ext_vector_type(8)));
typedef float f32x4  __attribute__((ext_vector_type(4)));

__device__ __forceinline__ void bsplit(float x, short& h, short& l) {
    unsigned u = __float_as_uint(x);
    h = (short)(u >> 16);
    float hf = __uint_as_float(u & 0xffff0000u);
    l = (short)(__float_as_uint(x - hf) >> 16);
}

// ---- merged pre-kernel: W split/transpose + per-graph adjacency build ----
__global__ __launch_bounds__(256) void prep(
    const float* __restrict__ W1, const float* __restrict__ W2,
    const float* __restrict__ W3, short* __restrict__ wt,
    const int* __restrict__ src, const int* __restrict__ dst,
    short* __restrict__ aint)
{
    const int tid = threadIdx.x;
    {
        const int i0 = blockIdx.x * blockDim.x + tid;
        const int stride = gridDim.x * blockDim.x;
        for (int e = i0; e < HID * RK1; e += stride) {
            int c = e / RK1, r = e % RK1;
            float v = (r < 3 * INF) ? W1[r * HID + c] : 0.f;
            short h, l; bsplit(v, h, l);
            wt[L1HI + e] = h;
            wt[L1LO + e] = l;
        }
        for (int e = i0; e < HID * RK2; e += stride) {
            int c = e / RK2, r = e % RK2;
            float v2 = (r < 3 * HID) ? W2[r * HID + c] : 0.f;
            float v3 = (r < 3 * HID) ? W3[r * HID + c] : 0.f;
            short h, l;
            bsplit(v2, h, l); wt[L2HI + e] = h; wt[L2LO + e] = l;
            bsplit(v3, h, l); wt[L3HI + e] = h; wt[L3LO + e] = l;
        }
    }
    __shared__ unsigned int cnt[AINT_SZ / 2];     // 25,600 B
    const int g = blockIdx.x, base = g * P;
    for (int i = tid; i < AINT_SZ / 2; i += 256) cnt[i] = 0u;
    __syncthreads();
    const int* srcg = src + g * EPG;
    const int* dstg = dst + g * EPG;
    for (int e = tid; e < EPG; e += 256) {
        int s = srcg[e] - base;
        int d = dstg[e] - base;
        int idx = d * AINT_K + s;
        atomicAdd(&cnt[idx >> 1], 1u << ((idx & 1) * 16));
    }
    __syncthreads();
    unsigned int* outw = (unsigned int*)(aint + (size_t)g * AINT_SZ);
    for (int i = tid; i < AINT_SZ / 2; i += 256) {
        unsigned int u = cnt[i];
        unsigned int b0 = __float_as_uint((float)(u & 0xffffu)) >> 16;
        unsigned int b1 = __float_as_uint((float)(u >> 16)) >> 16;
        outw[i] = b0 | (b1 << 16);
    }
}

// ---- one dense propagation: dst slot = -d^2*(Aint@src)  (SECOND: -2d^2*.. - Y)
template <int SECOND>
__device__ __forceinline__ void dense_prop(
    float* __restrict__ A, const short* __restrict__ aintg,
    int arow0, int arow1, bool has2,
    int srcoff, int dstoff, int ycol,
    int rb0, int rb1, f32x4 dv0, f32x4 dv1, int lane)
{
    const int n16 = lane & 15;
    const int q   = lane >> 4;
    const int kq  = q * 8;
    f32x4 p0, p1;
    p0[0]=0.f; p0[1]=0.f; p0[2]=0.f; p0[3]=0.f;
    p1[0]=0.f; p1[1]=0.f; p1[2]=0.f; p1[3]=0.f;
#pragma unroll
    for (int k = 0; k < 4; k++) {
        const short8 a0 = *(const short8*)&aintg[arow0 * AINT_K + k * 32 + kq];
        const short8 a1 = *(const short8*)&aintg[arow1 * AINT_K + k * 32 + kq];
        short8 bhi, blo; short h, l;
#pragma unroll
        for (int j = 0; j < 8; j++) {
            int row = k * 32 + kq + j;
            if (k == 3) row = (row < P) ? row : 0;   // Aint cols >=100 are 0
            float x = A[row * ASTR + srcoff + n16];
            bsplit(x, h, l); bhi[j] = h; blo[j] = l;
        }
        p0 = __builtin_amdgcn_mfma_f32_16x16x32_bf16(a0, bhi, p0, 0, 0, 0);
        p0 = __builtin_amdgcn_mfma_f32_16x16x32_bf16(a0, blo, p0, 0, 0, 0);
        if (has2) {
            p1 = __builtin_amdgcn_mfma_f32_16x16x32_bf16(a1, bhi, p1, 0, 0, 0);
            p1 = __builtin_amdgcn_mfma_f32_16x16x32_bf16(a1, blo, p1, 0, 0, 0);
        }
    }
#pragma unroll
    for (int r = 0; r < 4; r++) {
        const int row = rb0 + q * 4 + r;
        const float d2 = dv0[r] * dv0[r];
        float o;
        if (SECOND) o = -2.f * d2 * p0[r] - A[row * ASTR + ycol];
        else        o = -d2 * p0[r];
        A[row * ASTR + dstoff + n16] = o;
    }
    if (has2) {
#pragma unroll
        for (int r = 0; r < 4; r++) {
            const int row = rb1 + q * 4 + r;
            if (rb1 != 84 || row >= 96) {            // tile-6 overlap guard
                const float d2 = dv1[r] * dv1[r];
                float o;
                if (SECOND) o = -2.f * d2 * p1[r] - A[row * ASTR + ycol];
                else        o = -d2 * p1[r];
                A[row * ASTR + dstoff + n16] = o;
            }
        }
    }
}

// ---- one ChebConv layer ----
template <int F, int FINAL>
__device__ __forceinline__ void cheb_layer(
    float* __restrict__ A, const short* __restrict__ aintg,
    const short* __restrict__ whi, const short* __restrict__ wlo,
    const float* __restrict__ bias,
    int tid, int rb0, int rb1, bool has2, f32x4 dv0, f32x4 dv1)
{
    const int RK   = 3 * F + 16;
    const int lane = tid & 63;
    const int wv   = tid >> 6;
    const int n16  = lane & 15;
    const int q    = lane >> 4;
    const int ncol = (wv << 4) + n16;

    const int arow0 = rb0 + n16;
    const int arow1 = (has2 ? rb1 : rb0) + n16;

    f32x4 acc[7];
#pragma unroll
    for (int t = 0; t < 7; t++) { acc[t][0]=0.f; acc[t][1]=0.f; acc[t][2]=0.f; acc[t][3]=0.f; }

    for (int cb = 0; cb < F; cb += 16) {
        dense_prop<0>(A, aintg, arow0, arow1, has2, cb,    T1OFF, 0,
                      rb0, rb1, dv0, dv1, lane);
        __syncthreads();
        dense_prop<1>(A, aintg, arow0, arow1, has2, T1OFF, T2OFF, cb + n16,
                      rb0, rb1, dv0, dv1, lane);
        __syncthreads();

        // W partial: chunk K-layout [Y16 | T1_16 | T2_16 | zero16], 2 K-steps
#pragma unroll
        for (int ks = 0; ks < 2; ks++) {
            int wr, aoff;
            if (ks == 0) {
                wr   = (q == 0) ? cb : (q == 1) ? cb + 8 : (q == 2) ? F + cb : F + cb + 8;
                aoff = (q == 0) ? cb : (q == 1) ? cb + 8 : (q == 2) ? T1OFF  : T1OFF + 8;
            } else {
                wr   = (q == 0) ? 2*F + cb : (q == 1) ? 2*F + cb + 8 : (q == 2) ? 3*F : 3*F + 8;
                aoff = (q == 0) ? T2OFF    : (q == 1) ? T2OFF + 8    : (q == 2) ? T1OFF : T1OFF + 8;
            }
            const short8 bhi = *(const short8*)&whi[ncol * RK + wr];
            const short8 blo = *(const short8*)&wlo[ncol * RK + wr];
#pragma unroll
            for (int t = 0; t < 7; t++) {
                const int row = ((t < 6) ? t * 16 : 84) + n16;
                const float* xp = &A[row * ASTR + aoff];
                const float4 v0 = *(const float4*)xp;
                const float4 v1 = *(const float4*)(xp + 4);
                short8 ahi, alo; short h, l;
                bsplit(v0.x, h, l); ahi[0] = h; alo[0] = l;
                bsplit(v0.y, h, l); ahi[1] = h; alo[1] = l;
                bsplit(v0.z, h, l); ahi[2] = h; alo[2] = l;
                bsplit(v0.w, h, l); ahi[3] = h; alo[3] = l;
                bsplit(v1.x, h, l); ahi[4] = h; alo[4] = l;
                bsplit(v1.y, h, l); ahi[5] = h; alo[5] = l;
                bsplit(v1.z, h, l); ahi[6] = h; alo[6] = l;
                bsplit(v1.w, h, l); ahi[7] = h; alo[7] = l;
                acc[t] = __builtin_amdgcn_mfma_f32_16x16x32_bf16(ahi, bhi, acc[t], 0, 0, 0);
                acc[t] = __builtin_amdgcn_mfma_f32_16x16x32_bf16(ahi, blo, acc[t], 0, 0, 0);
                acc[t] = __builtin_amdgcn_mfma_f32_16x16x32_bf16(alo, bhi, acc[t], 0, 0, 0);
            }
        }
        __syncthreads();
    }

    // Epilogue (D: col=lane&15, row=4*(lane>>4)+reg; tile 6 -> rows 84..99)
    const float bcol = bias[ncol];
#pragma unroll
    for (int t = 0; t < 7; t++) {
        const int rbase = ((t < 6) ? t * 16 : 84) + q * 4;
#pragma unroll
        for (int r = 0; r < 4; r++) {
            const int row = rbase + r;
            if (t < 6 || row >= 96) {
                const float dn = A[row * ASTR + DINVC];
                const float v = acc[t][r];
                float o;
                if (FINAL) o = fmaxf(v * (1.0f / dn) + bcol, 0.f);
                else       o = fmaxf(v + bcol * dn, 0.f);
                A[row * ASTR + ncol] = o;
            }
        }
    }
    __syncthreads();
}

__global__ __launch_bounds__(256, 4) void gnn_kernel(
    const float* __restrict__ feat,
    const int* __restrict__ src, const int* __restrict__ dst,
    const float* __restrict__ b1, const float* __restrict__ b2,
    const float* __restrict__ b3,
    const float* __restrict__ Wfc, const float* __restrict__ bfc,
    const short* __restrict__ wt, const short* __restrict__ aint,
    float* __restrict__ out)
{
    __shared__ __align__(16) float A[P * ASTR];   // 40,000 B
    const int g = blockIdx.x;
    const int tid = threadIdx.x;
    const int base = g * P;
    const int* dstg = dst + g * EPG;

    // ---- degree count (col DEGC) ----
    for (int i = tid; i < P; i += 256) *(int*)&A[i * ASTR + DEGC] = 0;
    __syncthreads();
    for (int e = tid; e < EPG; e += 256) {
        int d = dstg[e] - base;
        atomicAdd((int*)&A[d * ASTR + DEGC], 1);
    }
    __syncthreads();
    for (int i = tid; i < P; i += 256) {
        int dg = *(int*)&A[i * ASTR + DEGC];
        A[i * ASTR + DINVC] = rsqrtf((float)(dg > 1 ? dg : 1));
    }
    __syncthreads();

    // ---- feat load prescaled (A = dinv*feat) ----
    for (int i = tid; i < P * INF / 4; i += 256) {
        int n = i >> 2, fq = (i & 3) * 4;
        float4 v = *(const float4*)&feat[(size_t)base * INF + i * 4];
        float dn = A[n * ASTR + DINVC];
        v.x *= dn; v.y *= dn; v.z *= dn; v.w *= dn;
        *(float4*)&A[n * ASTR + fq] = v;
    }
    __syncthreads();

    // ---- per-wave tile assignment + dinv preload for prop epilogues ----
    const int lane = tid & 63, wv = tid >> 6, q = lane >> 4;
    const int rb0 = wv * 16;
    const int t2i = wv + 4;
    const int rb1 = (t2i >= 6) ? 84 : t2i * 16;
    const bool has2 = (wv < 3);
    f32x4 dv0, dv1;
#pragma unroll
    for (int r = 0; r < 4; r++) {
        dv0[r] = A[(rb0 + q * 4 + r) * ASTR + DINVC];
        dv1[r] = A[((has2 ? rb1 : rb0) + q * 4 + r) * ASTR + DINVC];
    }

    const short* aintg = aint + (size_t)g * AINT_SZ;
    cheb_layer<INF, 0>(A, aintg, wt + L1HI, wt + L1LO, b1, tid, rb0, rb1, has2, dv0, dv1);
    cheb_layer<HID, 0>(A, aintg, wt + L2HI, wt + L2LO, b2, tid, rb0, rb1, has2, dv0, dv1);
    cheb_layer<HID, 1>(A, aintg, wt + L3HI, wt + L3LO, b3, tid, rb0, rb1, has2, dv0, dv1);

    // ---- mean pool + FC (psum in the now-free T1/T2 slots) ----
    {
        const int l2 = tid & 63, w = tid >> 6;
        float s = 0.f;
        for (int n = w; n < P; n += 4) s += A[n * ASTR + l2];
        A[l2 * ASTR + T1OFF + w] = s;
    }
    __syncthreads();
    if (tid < HID) {
        float hg = (A[tid * ASTR + T1OFF] + A[tid * ASTR + T1OFF + 1] +
                    A[tid * ASTR + T1OFF + 2] + A[tid * ASTR + T1OFF + 3]) * (1.0f / P);
        A[tid * ASTR + T1OFF + 4] = hg;
    }
    __syncthreads();
    if (tid < NOUT) {
        float o = bfc[tid];
        for (int c = 0; c < HID; c++) o += A[c * ASTR + T1OFF + 4] * Wfc[c * NOUT + tid];
        out[g * NOUT + tid] = o;
    }
}

extern "C" void kernel_launch(void* const* d_in, const int* in_sizes, int n_in,
                              void* d_out, int out_size, void* d_ws, size_t ws_size,
                              hipStream_t stream)
{
    const float* feat = (const float*)d_in[0];
    const int*   src  = (const int*)d_in[1];
    const int*   dst  = (const int*)d_in[2];
    const float* W1  = (const float*)d_in[5];
    const float* b1  = (const float*)d_in[6];
    const float* W2  = (const float*)d_in[7];
    const float* b2  = (const float*)d_in[8];
    const float* W3  = (const float*)d_in[9];
    const float* b3  = (const float*)d_in[10];
    const float* Wfc = (const float*)d_in[11];
    const float* bfc = (const float*)d_in[12];
    float* out = (float*)d_out;

    short* wt   = (short*)d_ws;                 // 122,880 B
    short* aint = wt + WT_SHORTS;               // + 25,600,000 B

    prep<<<NGRAPH, 256, 0, stream>>>(W1, W2, W3, wt, src, dst, aint);
    gnn_kernel<<<NGRAPH, 256, 0, stream>>>(feat, src, dst,
                                           b1, b2, b3, Wfc, bfc, wt, aint, out);
}